// Round 8
// baseline (544.174 us; speedup 1.0000x reference)
//
#include <hip/hip_runtime.h>

typedef unsigned short u16;
typedef unsigned int u32;
typedef __attribute__((ext_vector_type(8))) short bf16x8;
typedef __attribute__((ext_vector_type(4))) float f32x4;
typedef __attribute__((ext_vector_type(4))) int i32x4;
typedef __attribute__((ext_vector_type(2))) unsigned int u32x2;

// T=4096 tokens, D=1024, F=4096, E=8, K=2. Inputs fp32.
// ws: xb(8M) | H(64M) | w1t(64M) | w3t(64M) | w2t(64M) | wa/alist/cnt

__device__ __forceinline__ u16 f2bf(float f) {
  u32 u = __builtin_bit_cast(u32, f);
  u += 0x7fffu + ((u >> 16) & 1u);
  return (u16)(u >> 16);
}
__device__ __forceinline__ u32 pack2(u16 a, u16 b) { return (u32)a | ((u32)b << 16); }

// XOR-swizzled LDS byte address for [row][64 bf16] GEMM tiles (128B rows); 16B-unit swizzle.
__device__ __forceinline__ char* lds_swz(void* base, int row, int byteInRow) {
  return (char*)base + (((row << 7) + byteInRow) ^ ((row & 7) << 4));
}

// async global->LDS, 16B per lane; LDS dest = wave-uniform base + lane*16, global src per-lane.
#define GLL16(g, l) __builtin_amdgcn_global_load_lds( \
    (const __attribute__((address_space(1))) void*)(g), \
    (__attribute__((address_space(3))) void*)(l), 16, 0, 0)

// ---- transposing fp32->bf16 converter: NT consecutive 64x64 tiles (fixed c0, rows r0base+t*64) ----
__device__ __forceinline__ void trans_tiles(
    const float* __restrict__ src, u16* __restrict__ dst,
    int Cs, int Rs, int c0, int r0base, int NT, float* lds /* [2][4096] */)
{
  const int tid = threadIdx.x;
  const int w = tid >> 6, l = tid & 63;
  const float* sbase = src + (size_t)(r0base + w * 16 + (l >> 4)) * Cs + c0 + (l & 15) * 4;
  const int c = tid & 63, rseg = tid >> 6;

#pragma unroll
  for (int q = 0; q < 4; ++q)
    GLL16(sbase + (size_t)(q * 4) * Cs, lds + (w * 16 + q * 4) * 64);

  for (int t = 0; t < NT; ++t) {
    if (t + 1 < NT) {
      const float* sb2 = sbase + (size_t)((t + 1) * 64) * Cs;
      float* lb2 = lds + ((t + 1) & 1) * 4096;
#pragma unroll
      for (int q = 0; q < 4; ++q)
        GLL16(sb2 + (size_t)(q * 4) * Cs, lb2 + (w * 16 + q * 4) * 64);
      asm volatile("s_waitcnt vmcnt(4)" ::: "memory");
    } else {
      asm volatile("s_waitcnt vmcnt(0)" ::: "memory");
    }
    __builtin_amdgcn_s_barrier();
    const float* tb = lds + (t & 1) * 4096;
    u32 p[8];
#pragma unroll
    for (int i = 0; i < 8; ++i) {
      float a  = tb[(rseg * 16 + 2 * i) * 64 + c];
      float bv = tb[(rseg * 16 + 2 * i + 1) * 64 + c];
      p[i] = pack2(f2bf(a), f2bf(bv));
    }
    u16* dp = dst + (size_t)(c0 + c) * Rs + r0base + t * 64 + rseg * 16;
    *(i32x4*)dp = *(i32x4*)&p[0];
    *(i32x4*)(dp + 8) = *(i32x4*)&p[4];
    asm volatile("s_waitcnt lgkmcnt(0)" ::: "memory");
    __builtin_amdgcn_s_barrier();
  }
}

// ---- gemm1 block body (R3-proven): tile 128M x (64+64)N at N-tile (nbase+bx) ----
__device__ __forceinline__ void gemm1_body(
    char* smem, const u16* __restrict__ xb, const u16* __restrict__ w1t, const u16* __restrict__ w3t,
    const int* __restrict__ alist, const int* __restrict__ cnt, u16* __restrict__ H,
    int e, int nbase)
{
  u16* As = (u16*)smem;                  // [128*64]
  u16* Bs = (u16*)(smem + 16384);        // [2][64*64]
  int* rowid = (int*)(smem + 32768);     // [128]

  const int mc = cnt[e];
  const int m0 = blockIdx.y * 128;
  if (m0 >= mc) return;
  const int n0 = (nbase + blockIdx.x) * 64;
  const int tid = threadIdx.x;

  if (tid < 128) rowid[tid] = (m0 + tid < mc) ? alist[e * 4096 + m0 + tid] : -1;
  __syncthreads();

  const int l = tid & 63, w = tid >> 6;
  const u16* wt = (w >> 1) ? w3t : w1t;
  u16* bbase = Bs + (w >> 1) * 4096;

  const u16* aps[4]; const u16* bps[4];
  u16* ald[4]; u16* bld[4];
#pragma unroll
  for (int q = 0; q < 4; ++q) {
    int ra = 32 * w + 8 * q + (l >> 3);
    int id = rowid[ra];
    aps[q] = xb + (size_t)(id < 0 ? 0 : (id >> 1)) * 1024 + ((l & 7) ^ (ra & 7)) * 8;
    ald[q] = As + (32 * w + 8 * q) * 64;
    int rb = 32 * (w & 1) + 8 * q + (l >> 3);
    bps[q] = wt + (size_t)e * 4194304 + (size_t)(n0 + rb) * 1024 + ((l & 7) ^ (rb & 7)) * 8;
    bld[q] = bbase + (32 * (w & 1) + 8 * q) * 64;
  }

  const int wm = (w >> 1) * 64, wn = (w & 1) * 32;
  const int l15 = l & 15, lg = l >> 4;

  f32x4 acc1[4][2], acc3[4][2];
  const f32x4 zf = {0.f, 0.f, 0.f, 0.f};
#pragma unroll
  for (int mi = 0; mi < 4; ++mi) { acc1[mi][0] = zf; acc1[mi][1] = zf; acc3[mi][0] = zf; acc3[mi][1] = zf; }

  for (int kt = 0; kt < 16; ++kt) {
    const int ko = kt * 64;
#pragma unroll
    for (int q = 0; q < 4; ++q) GLL16(aps[q] + ko, ald[q]);
#pragma unroll
    for (int q = 0; q < 4; ++q) GLL16(bps[q] + ko, bld[q]);
    __syncthreads();
#pragma unroll
    for (int ks = 0; ks < 2; ++ks) {
      const int kb = ks * 64 + lg * 16;
      bf16x8 af[4];
#pragma unroll
      for (int mi = 0; mi < 4; ++mi)
        af[mi] = *(const bf16x8*)lds_swz(As, wm + mi * 16 + l15, kb);
#pragma unroll
      for (int ni = 0; ni < 2; ++ni) {
        bf16x8 b1 = *(const bf16x8*)lds_swz(Bs, wn + ni * 16 + l15, kb);
        bf16x8 b3 = *(const bf16x8*)lds_swz(Bs + 4096, wn + ni * 16 + l15, kb);
#pragma unroll
        for (int mi = 0; mi < 4; ++mi) {
          acc1[mi][ni] = __builtin_amdgcn_mfma_f32_16x16x32_bf16(af[mi], b1, acc1[mi][ni], 0, 0, 0);
          acc3[mi][ni] = __builtin_amdgcn_mfma_f32_16x16x32_bf16(af[mi], b3, acc3[mi][ni], 0, 0, 0);
        }
      }
    }
    __syncthreads();
  }

#pragma unroll
  for (int mi = 0; mi < 4; ++mi) {
    const int rb = wm + mi * 16 + lg * 4;
#pragma unroll
    for (int ni = 0; ni < 2; ++ni) {
      const int col = n0 + wn + ni * 16 + l15;
      f32x4 c1 = acc1[mi][ni], c3 = acc3[mi][ni];
#pragma unroll
      for (int j = 0; j < 4; ++j) {
        int id = rowid[rb + j];
        if (id >= 0) {
          float a = c1[j];
          float h = (a / (1.f + __expf(-a))) * c3[j];
          H[(size_t)id * 4096 + col] = f2bf(h);
        }
      }
    }
  }
}

// ---------------- L1: router + w1/w3 prep of cols 0..1023 ----------------
__global__ __launch_bounds__(256) void l1_k(
    const float* __restrict__ w1, const float* __restrict__ w3,
    u16* __restrict__ w1t, u16* __restrict__ w3t,
    const float* __restrict__ x, const float* __restrict__ gw,
    float* __restrict__ probs, u16* __restrict__ xb,
    float* __restrict__ wa, int* __restrict__ alist, int* __restrict__ cnt)
{
  __shared__ __align__(16) float smem[2][4096];   // 32 KiB
  const int bid = blockIdx.x;
  if (bid >= 4096) {
    const int t0 = bid - 4096;          // 0..511
    const int sel = t0 >> 8;
    const int rem = t0 & 255;
    const int e = rem >> 5;
    const int rem2 = rem & 31;
    const int ct = rem2 >> 1;           // 0..15 -> cols 0..1023
    const int rh = rem2 & 1;
    const float* src = (sel ? w3 : w1) + (size_t)e * 4194304;
    u16* dst = (sel ? w3t : w1t) + (size_t)e * 4194304;
    trans_tiles(src, dst, 4096, 1024, ct * 64, rh * 512, 8, &smem[0][0]);
    return;
  }
  // ---- router block
  const int t = bid;
  const int tid = threadIdx.x;
  f32x4 xv = ((const f32x4*)(x + (size_t)t * 1024))[tid];
  u32x2 hb;
  hb[0] = pack2(f2bf(xv[0]), f2bf(xv[1]));
  hb[1] = pack2(f2bf(xv[2]), f2bf(xv[3]));
  *(u32x2*)(xb + (size_t)t * 1024 + tid * 4) = hb;

  float acc[8];
#pragma unroll
  for (int e = 0; e < 8; ++e) acc[e] = 0.f;
  const float* g = gw + tid * 32;
#pragma unroll
  for (int j = 0; j < 4; ++j)
#pragma unroll
    for (int e = 0; e < 8; ++e) acc[e] = fmaf(xv[j], g[j * 8 + e], acc[e]);

#pragma unroll
  for (int e = 0; e < 8; ++e)
    for (int off = 32; off > 0; off >>= 1) acc[e] += __shfl_down(acc[e], off);

  float* red = &smem[0][0];
  const int lane = tid & 63, wid = tid >> 6;
  if (lane == 0) {
#pragma unroll
    for (int e = 0; e < 8; ++e) red[wid * 8 + e] = acc[e];
  }
  __syncthreads();
  if (tid == 0) {
    float p[8]; float mx = -1e30f;
#pragma unroll
    for (int e = 0; e < 8; ++e) { p[e] = red[e] + red[8 + e] + red[16 + e] + red[24 + e]; mx = fmaxf(mx, p[e]); }
    float s = 0.f;
#pragma unroll
    for (int e = 0; e < 8; ++e) { p[e] = __expf(p[e] - mx); s += p[e]; }
    float inv = 1.f / s;
#pragma unroll
    for (int e = 0; e < 8; ++e) { p[e] *= inv; probs[(size_t)t * 8 + e] = p[e]; }
    int i0 = 0;
#pragma unroll
    for (int e = 1; e < 8; ++e) if (p[e] > p[i0]) i0 = e;
    int i1 = (i0 == 0) ? 1 : 0;
#pragma unroll
    for (int e = 0; e < 8; ++e) if (e != i0 && p[e] > p[i1]) i1 = e;
    float s2 = p[i0] + p[i1];
    int pos0 = atomicAdd(&cnt[i0], 1); alist[i0 * 4096 + pos0] = t * 2;
    int pos1 = atomicAdd(&cnt[i1], 1); alist[i1 * 4096 + pos1] = t * 2 + 1;
    wa[t * 2]     = p[i0] / s2;
    wa[t * 2 + 1] = p[i1] / s2;
  }
}

// ---------------- L2: gemm1 N-tiles 0..15 + w1/w3 prep cols 1024..4095 ----------------
__global__ __launch_bounds__(256, 2) void l2_k(
    const u16* __restrict__ xb, const u16* __restrict__ w1t, const u16* __restrict__ w3t,
    const int* __restrict__ alist, const int* __restrict__ cnt, u16* __restrict__ H,
    const float* __restrict__ w1, const float* __restrict__ w3,
    u16* __restrict__ w1to, u16* __restrict__ w3to)
{
  __shared__ __align__(16) char smem[33280];
  const int bx = blockIdx.x;
  if (bx >= 16) {
    const int slot = (bx - 16) * 256 + blockIdx.y * 8 + blockIdx.z;  // 0..1535
    const int sel = slot >= 768;
    const int r = sel ? (slot - 768) : slot;
    const int e = r / 96;
    const int r2 = r - e * 96;
    const int ct = 16 + (r2 >> 1);      // 16..63 -> cols 1024..4095
    const int rh = r2 & 1;
    const float* src = (sel ? w3 : w1) + (size_t)e * 4194304;
    u16* dst = (sel ? w3to : w1to) + (size_t)e * 4194304;
    trans_tiles(src, dst, 4096, 1024, ct * 64, rh * 512, 8, (float*)smem);
    return;
  }
  gemm1_body(smem, xb, w1t, w3t, alist, cnt, H, blockIdx.z, 0);
}

// ---------------- L3: gemm1 N-tiles 16..63 + full w2 prep ----------------
__global__ __launch_bounds__(256, 2) void l3_k(
    const u16* __restrict__ xb, const u16* __restrict__ w1t, const u16* __restrict__ w3t,
    const int* __restrict__ alist, const int* __restrict__ cnt, u16* __restrict__ H,
    const float* __restrict__ w2, u16* __restrict__ w2t)
{
  __shared__ __align__(16) char smem[33280];
  const int bx = blockIdx.x;
  if (bx >= 48) {
    const int slot = (bx - 48) * 256 + blockIdx.y * 8 + blockIdx.z;  // 0..2047
    const int e2 = slot >> 8;
    const int idx = slot & 255;
    const float* src = w2 + (size_t)e2 * 4194304;
    u16* dst = w2t + (size_t)e2 * 4194304;
    trans_tiles(src, dst, 1024, 4096, (idx >> 4) * 64, (idx & 15) * 256, 4, (float*)smem);
    return;
  }
  gemm1_body(smem, xb, w1t, w3t, alist, cnt, H, blockIdx.z, 16);
}

// ---------------- gemm2: out[token] += wa * (H @ w2), split-K=2, fused combine ----------------
__global__ __launch_bounds__(256, 2) void gemm2_k(
    const u16* __restrict__ H, const u16* __restrict__ w2t,
    const int* __restrict__ alist, const int* __restrict__ cnt,
    const float* __restrict__ wa, float* __restrict__ out)
{
  const int e = blockIdx.z;
  const int mc = cnt[e];
  const int yy = blockIdx.y;
  const int kh = yy & 1;
  const int m0 = (yy >> 1) * 128;
  if (m0 >= mc) return;
  const int n0 = blockIdx.x * 128;
  const int tid = threadIdx.x;

  __shared__ u16 As[128 * 64];
  __shared__ u16 Bs[128 * 64];
  __shared__ int rowid[128];
  __shared__ float rw[128];

  if (tid < 128) {
    int id = (m0 + tid < mc) ? alist[e * 4096 + m0 + tid] : -1;
    rowid[tid] = id;
    rw[tid] = (id >= 0) ? wa[id] : 0.f;
  }
  __syncthreads();

  const int l = tid & 63, w = tid >> 6;
  const size_t kbase = (size_t)kh * 2048;
  const u16* aps[4]; const u16* bps[4];
  u16* ald[4]; u16* bld[4];
#pragma unroll
  for (int q = 0; q < 4; ++q) {
    int ra = 32 * w + 8 * q + (l >> 3);
    int id = rowid[ra];
    aps[q] = H + (size_t)(id < 0 ? 0 : id) * 4096 + kbase + ((l & 7) ^ (ra & 7)) * 8;
    ald[q] = As + (32 * w + 8 * q) * 64;
    int rb = 32 * w + 8 * q + (l >> 3);
    bps[q] = w2t + (size_t)e * 4194304 + (size_t)(n0 + rb) * 4096 + kbase + ((l & 7) ^ (rb & 7)) * 8;
    bld[q] = Bs + (32 * w + 8 * q) * 64;
  }

  const int wm = (w >> 1) * 64, wn = (w & 1) * 64;
  const int l15 = l & 15, lg = l >> 4;

  f32x4 acc[4][4];
  const f32x4 zf = {0.f, 0.f, 0.f, 0.f};
#pragma unroll
  for (int mi = 0; mi < 4; ++mi)
#pragma unroll
    for (int ni = 0; ni < 4; ++ni) acc[mi][ni] = zf;

  for (int kt = 0; kt < 32; ++kt) {
    const int ko = kt * 64;
#pragma unroll
    for (int q = 0; q < 4; ++q) GLL16(aps[q] + ko, ald[q]);
#pragma unroll
    for (int q = 0; q < 4; ++q) GLL16(bps[q] + ko, bld[q]);
    __syncthreads();
#pragma unroll
    for (int ks = 0; ks < 2; ++ks) {
      const int kb = ks * 64 + lg * 16;
      bf16x8 af[4];
#pragma unroll
      for (int mi = 0; mi < 4; ++mi)
        af[mi] = *(const bf16x8*)lds_swz(As, wm + mi * 16 + l15, kb);
#pragma unroll
      for (int ni = 0; ni < 4; ++ni) {
        bf16x8 bfb = *(const bf16x8*)lds_swz(Bs, wn + ni * 16 + l15, kb);
#pragma unroll
        for (int mi = 0; mi < 4; ++mi)
          acc[mi][ni] = __builtin_amdgcn_mfma_f32_16x16x32_bf16(af[mi], bfb, acc[mi][ni], 0, 0, 0);
      }
    }
    __syncthreads();
  }

#pragma unroll
  for (int mi = 0; mi < 4; ++mi) {
    const int rb = wm + mi * 16 + lg * 4;
#pragma unroll
    for (int ni = 0; ni < 4; ++ni) {
      const int col = n0 + wn + ni * 16 + l15;
      f32x4 c = acc[mi][ni];
#pragma unroll
      for (int j = 0; j < 4; ++j) {
        int rr = rb + j;
        int id = rowid[rr];
        if (id >= 0)
          unsafeAtomicAdd(&out[(size_t)(id >> 1) * 1024 + col], c[j] * rw[rr]);
      }
    }
  }
}

extern "C" void kernel_launch(void* const* d_in, const int* in_sizes, int n_in,
                              void* d_out, int out_size, void* d_ws, size_t ws_size,
                              hipStream_t stream)
{
  (void)in_sizes; (void)n_in; (void)out_size; (void)ws_size;
  const float* x  = (const float*)d_in[0];
  const float* gw = (const float*)d_in[1];
  const float* w1 = (const float*)d_in[2];
  const float* w3 = (const float*)d_in[3];
  const float* w2 = (const float*)d_in[4];
  float* out   = (float*)d_out;
  float* probs = out + (size_t)4096 * 1024;

  const size_t MB = (size_t)1 << 20;
  char* ws = (char*)d_ws;
  u16*   xb    = (u16*)(ws);
  u16*   H     = (u16*)(ws + 8 * MB);
  u16*   w1t   = (u16*)(ws + 72 * MB);
  u16*   w3t   = (u16*)(ws + 136 * MB);
  u16*   w2t   = (u16*)(ws + 200 * MB);
  float* wa    = (float*)(ws + 264 * MB);
  int*   alist = (int*)(ws + 264 * MB + 32768);
  int*   cnt   = (int*)(ws + 264 * MB + 32768 + 131072);

  hipMemsetAsync(cnt, 0, 8 * sizeof(int), stream);
  hipMemsetAsync(out, 0, (size_t)4096 * 1024 * sizeof(float), stream);
  l1_k<<<4608, 256, 0, stream>>>(w1, w3, w1t, w3t, x, gw, probs, xb, wa, alist, cnt);
  l2_k<<<dim3(22, 32, 8), 256, 0, stream>>>(xb, w1t, w3t, alist, cnt, H, w1, w3, w1t, w3t);
  l3_k<<<dim3(56, 32, 8), 256, 0, stream>>>(xb, w1t, w3t, alist, cnt, H, w2, w2t);
  gemm2_k<<<dim3(8, 64, 8), 256, 0, stream>>>(H, w2t, alist, cnt, wa, out);
}

// Round 9
// 500.931 us; speedup vs baseline: 1.0863x; 1.0863x over previous
//
#include <hip/hip_runtime.h>

typedef unsigned short u16;
typedef unsigned int u32;
typedef __attribute__((ext_vector_type(8))) short bf16x8;
typedef __attribute__((ext_vector_type(4))) float f32x4;
typedef __attribute__((ext_vector_type(4))) int i32x4;
typedef __attribute__((ext_vector_type(2))) unsigned int u32x2;

// T=4096 tokens, D=1024, F=4096, E=8, K=2. Inputs fp32.
// Weight scratch layout: TILED bf16. w1t/w3t: [e][nt=64][kt=16][64n][64k] (tile=8KB contig)
//                                   w2t:     [e][nt=16][kt=64][64n][64k]
// ws: xb(8M) | H(64M) | w1t(64M) | w3t(64M) | w2t(64M) | wa/alist/cnt

__device__ __forceinline__ u16 f2bf(float f) {
  u32 u = __builtin_bit_cast(u32, f);
  u += 0x7fffu + ((u >> 16) & 1u);
  return (u16)(u >> 16);
}
__device__ __forceinline__ u32 pack2(u16 a, u16 b) { return (u32)a | ((u32)b << 16); }

// XOR-swizzled LDS byte address for [row][64 bf16] GEMM tiles (128B rows); 16B-unit swizzle.
__device__ __forceinline__ char* lds_swz(void* base, int row, int byteInRow) {
  return (char*)base + (((row << 7) + byteInRow) ^ ((row & 7) << 4));
}

// async global->LDS, 16B per lane; LDS dest = wave-uniform base + lane*16, global src per-lane.
#define GLL16(g, l) __builtin_amdgcn_global_load_lds( \
    (const __attribute__((address_space(1))) void*)(g), \
    (__attribute__((address_space(3))) void*)(l), 16, 0, 0)

// ---------------- launch A: router + w1/w3 tiled prep ----------------
// prep block: stage 64 rows x 256 cols fp32 (1KB contiguous per row), write 4 x 8KB contig bf16 tiles.
__global__ __launch_bounds__(256) void prep13_k(
    const float* __restrict__ w1, const float* __restrict__ w3,
    u16* __restrict__ w1t, u16* __restrict__ w3t,
    const float* __restrict__ x, const float* __restrict__ gw,
    float* __restrict__ probs, u16* __restrict__ xb,
    float* __restrict__ wa, int* __restrict__ alist, int* __restrict__ cnt)
{
  __shared__ __align__(16) float smem[16384];   // 64 KiB
  const int bid = blockIdx.x;
  const int tid = threadIdx.x;
  if (bid >= 4096) {
    const int t0 = bid - 4096;              // 0..4095
    const int sel = t0 >> 11;               // 0:w1 1:w3
    const int e   = (t0 >> 8) & 7;
    const int ktb = (t0 >> 4) & 15;         // k rows ktb*64
    const int nc  = t0 & 15;                // cols nc*256
    const float* src = (sel ? w3 : w1) + (size_t)e * 4194304 + (size_t)(ktb * 64) * 4096 + nc * 256;
    u16* dstb = (sel ? w3t : w1t) + (size_t)e * 64 * 16 * 4096 + (size_t)ktb * 4096;

    const int w = tid >> 6, l = tid & 63;
#pragma unroll
    for (int q = 0; q < 16; ++q) {
      const int r = w * 16 + q;
      GLL16(src + (size_t)r * 4096 + l * 4, smem + r * 256);
    }
    asm volatile("s_waitcnt vmcnt(0)" ::: "memory");
    __syncthreads();

    // thread t: output row n = t&63 of subtile s = t>>6 (src col cc = t)
    u32 p[32];
#pragma unroll
    for (int i = 0; i < 32; ++i) {
      float a = smem[(2 * i) * 256 + tid];
      float b = smem[(2 * i + 1) * 256 + tid];
      p[i] = pack2(f2bf(a), f2bf(b));
    }
    const int s = tid >> 6, n = tid & 63;
    u16* dp = dstb + (size_t)(nc * 4 + s) * 16 * 4096 + n * 64;
#pragma unroll
    for (int k = 0; k < 8; ++k)
      *(i32x4*)(dp + k * 8) = *(const i32x4*)&p[k * 4];
    return;
  }
  // ---- router block
  const int t = bid;
  f32x4 xv = ((const f32x4*)(x + (size_t)t * 1024))[tid];
  u32x2 hb;
  hb[0] = pack2(f2bf(xv[0]), f2bf(xv[1]));
  hb[1] = pack2(f2bf(xv[2]), f2bf(xv[3]));
  *(u32x2*)(xb + (size_t)t * 1024 + tid * 4) = hb;

  float acc[8];
#pragma unroll
  for (int e = 0; e < 8; ++e) acc[e] = 0.f;
  const float* g = gw + tid * 32;
#pragma unroll
  for (int j = 0; j < 4; ++j)
#pragma unroll
    for (int e = 0; e < 8; ++e) acc[e] = fmaf(xv[j], g[j * 8 + e], acc[e]);

#pragma unroll
  for (int e = 0; e < 8; ++e)
    for (int off = 32; off > 0; off >>= 1) acc[e] += __shfl_down(acc[e], off);

  float* red = smem;
  const int lane = tid & 63, wid = tid >> 6;
  if (lane == 0) {
#pragma unroll
    for (int e = 0; e < 8; ++e) red[wid * 8 + e] = acc[e];
  }
  __syncthreads();
  if (tid == 0) {
    float p[8]; float mx = -1e30f;
#pragma unroll
    for (int e = 0; e < 8; ++e) { p[e] = red[e] + red[8 + e] + red[16 + e] + red[24 + e]; mx = fmaxf(mx, p[e]); }
    float s = 0.f;
#pragma unroll
    for (int e = 0; e < 8; ++e) { p[e] = __expf(p[e] - mx); s += p[e]; }
    float inv = 1.f / s;
#pragma unroll
    for (int e = 0; e < 8; ++e) { p[e] *= inv; probs[(size_t)t * 8 + e] = p[e]; }
    int i0 = 0;
#pragma unroll
    for (int e = 1; e < 8; ++e) if (p[e] > p[i0]) i0 = e;
    int i1 = (i0 == 0) ? 1 : 0;
#pragma unroll
    for (int e = 0; e < 8; ++e) if (e != i0 && p[e] > p[i1]) i1 = e;
    float s2 = p[i0] + p[i1];
    int pos0 = atomicAdd(&cnt[i0], 1); alist[i0 * 4096 + pos0] = t * 2;
    int pos1 = atomicAdd(&cnt[i1], 1); alist[i1 * 4096 + pos1] = t * 2 + 1;
    wa[t * 2]     = p[i0] / s2;
    wa[t * 2 + 1] = p[i1] / s2;
  }
}

// ---------------- launch B: gemm1 (tiled B) + w2 tiled prep overlaid ----------------
// bx<64: gemm1 N-tile bx; bx 64..79: w2 prep (64k x 128n per block).
__global__ __launch_bounds__(256, 2) void gemm1w2_k(
    const u16* __restrict__ xb, const u16* __restrict__ w1t, const u16* __restrict__ w3t,
    const int* __restrict__ alist, const int* __restrict__ cnt, u16* __restrict__ H,
    const float* __restrict__ w2, u16* __restrict__ w2t)
{
  __shared__ __align__(16) char smem[33280];
  const int e = blockIdx.z;
  const int bx = blockIdx.x;
  const int tid = threadIdx.x;

  if (bx >= 64) {
    const int slot = ((bx - 64) * 32 + blockIdx.y) * 8 + e;  // 0..4095
    const int e2  = slot >> 9;
    const int ktb = (slot >> 3) & 63;          // k rows ktb*64
    const int nc  = slot & 7;                  // cols nc*128
    const float* src = w2 + (size_t)e2 * 4194304 + (size_t)(ktb * 64) * 1024 + nc * 128;
    float* lds = (float*)smem;                 // [64][128] fp32 = 32 KB

    const int w = tid >> 6, l = tid & 63;
#pragma unroll
    for (int q = 0; q < 8; ++q) {
      const int r2 = w * 8 + q;                // row pair: rows 2*r2, 2*r2+1
      GLL16(src + (size_t)(2 * r2 + (l >> 5)) * 1024 + (l & 31) * 4, lds + r2 * 256);
    }
    asm volatile("s_waitcnt vmcnt(0)" ::: "memory");
    __syncthreads();

    // thread t: subtile s=(t>>6)&1, out row n=t&63, k half kh2=t>>7
    const int s = (tid >> 6) & 1, n = tid & 63, kh2 = tid >> 7;
    const int cc = s * 64 + n;
    u32 p[16];
#pragma unroll
    for (int i = 0; i < 16; ++i) {
      float a = lds[(kh2 * 32 + 2 * i) * 128 + cc];
      float b = lds[(kh2 * 32 + 2 * i + 1) * 128 + cc];
      p[i] = pack2(f2bf(a), f2bf(b));
    }
    u16* dp = w2t + (((size_t)e2 * 16 + nc * 2 + s) * 64 + ktb) * 4096 + n * 64 + kh2 * 32;
#pragma unroll
    for (int k = 0; k < 4; ++k)
      *(i32x4*)(dp + k * 8) = *(const i32x4*)&p[k * 4];
    return;
  }

  u16* As = (u16*)smem;                  // [128*64]
  u16* Bs = (u16*)(smem + 16384);        // [2][64*64]
  int* rowid = (int*)(smem + 32768);     // [128]

  const int mc = cnt[e];
  const int m0 = blockIdx.y * 128;
  if (m0 >= mc) return;
  const int n0 = bx * 64;

  if (tid < 128) rowid[tid] = (m0 + tid < mc) ? alist[e * 4096 + m0 + tid] : -1;
  __syncthreads();

  const int l = tid & 63, w = tid >> 6;
  const u16* wt = (w >> 1) ? w3t : w1t;
  u16* bbase = Bs + (w >> 1) * 4096;

  const u16* aps[4]; const u16* bps[4];
  u16* ald[4]; u16* bld[4];
#pragma unroll
  for (int q = 0; q < 4; ++q) {
    int ra = 32 * w + 8 * q + (l >> 3);
    int id = rowid[ra];
    aps[q] = xb + (size_t)(id < 0 ? 0 : (id >> 1)) * 1024 + ((l & 7) ^ (ra & 7)) * 8;
    ald[q] = As + (32 * w + 8 * q) * 64;
    int rb = 32 * (w & 1) + 8 * q + (l >> 3);
    bps[q] = wt + ((size_t)e * 64 + bx) * 16 * 4096 + rb * 64 + ((l & 7) ^ (rb & 7)) * 8;
    bld[q] = bbase + (32 * (w & 1) + 8 * q) * 64;
  }

  const int wm = (w >> 1) * 64, wn = (w & 1) * 32;
  const int l15 = l & 15, lg = l >> 4;

  f32x4 acc1[4][2], acc3[4][2];
  const f32x4 zf = {0.f, 0.f, 0.f, 0.f};
#pragma unroll
  for (int mi = 0; mi < 4; ++mi) { acc1[mi][0] = zf; acc1[mi][1] = zf; acc3[mi][0] = zf; acc3[mi][1] = zf; }

  for (int kt = 0; kt < 16; ++kt) {
#pragma unroll
    for (int q = 0; q < 4; ++q) GLL16(aps[q] + kt * 64, ald[q]);
#pragma unroll
    for (int q = 0; q < 4; ++q) GLL16(bps[q] + kt * 4096, bld[q]);
    __syncthreads();
#pragma unroll
    for (int ks = 0; ks < 2; ++ks) {
      const int kb = ks * 64 + lg * 16;
      bf16x8 af[4];
#pragma unroll
      for (int mi = 0; mi < 4; ++mi)
        af[mi] = *(const bf16x8*)lds_swz(As, wm + mi * 16 + l15, kb);
#pragma unroll
      for (int ni = 0; ni < 2; ++ni) {
        bf16x8 b1 = *(const bf16x8*)lds_swz(Bs, wn + ni * 16 + l15, kb);
        bf16x8 b3 = *(const bf16x8*)lds_swz(Bs + 4096, wn + ni * 16 + l15, kb);
#pragma unroll
        for (int mi = 0; mi < 4; ++mi) {
          acc1[mi][ni] = __builtin_amdgcn_mfma_f32_16x16x32_bf16(af[mi], b1, acc1[mi][ni], 0, 0, 0);
          acc3[mi][ni] = __builtin_amdgcn_mfma_f32_16x16x32_bf16(af[mi], b3, acc3[mi][ni], 0, 0, 0);
        }
      }
    }
    __syncthreads();
  }

#pragma unroll
  for (int mi = 0; mi < 4; ++mi) {
    const int rb = wm + mi * 16 + lg * 4;
#pragma unroll
    for (int ni = 0; ni < 2; ++ni) {
      const int col = n0 + wn + ni * 16 + l15;
      f32x4 c1 = acc1[mi][ni], c3 = acc3[mi][ni];
#pragma unroll
      for (int j = 0; j < 4; ++j) {
        int id = rowid[rb + j];
        if (id >= 0) {
          float a = c1[j];
          float h = (a / (1.f + __expf(-a))) * c3[j];
          H[(size_t)id * 4096 + col] = f2bf(h);
        }
      }
    }
  }
}

// ---------------- gemm2: out[token] += wa * (H @ w2), split-K=2, fused combine, tiled B ----------------
__global__ __launch_bounds__(256, 2) void gemm2_k(
    const u16* __restrict__ H, const u16* __restrict__ w2t,
    const int* __restrict__ alist, const int* __restrict__ cnt,
    const float* __restrict__ wa, float* __restrict__ out)
{
  const int e = blockIdx.z;
  const int mc = cnt[e];
  const int yy = blockIdx.y;
  const int kh = yy & 1;
  const int m0 = (yy >> 1) * 128;
  if (m0 >= mc) return;
  const int n0 = blockIdx.x * 128;
  const int tid = threadIdx.x;

  __shared__ u16 As[128 * 64];
  __shared__ u16 Bs[128 * 64];
  __shared__ int rowid[128];
  __shared__ float rw[128];

  if (tid < 128) {
    int id = (m0 + tid < mc) ? alist[e * 4096 + m0 + tid] : -1;
    rowid[tid] = id;
    rw[tid] = (id >= 0) ? wa[id] : 0.f;
  }
  __syncthreads();

  const int l = tid & 63, w = tid >> 6;
  const size_t kbase = (size_t)kh * 2048;
  const u16* aps[4]; const u16* bps[4];
  u16* ald[4]; u16* bld[4];
#pragma unroll
  for (int q = 0; q < 4; ++q) {
    int ra = 32 * w + 8 * q + (l >> 3);
    int id = rowid[ra];
    aps[q] = H + (size_t)(id < 0 ? 0 : id) * 4096 + kbase + ((l & 7) ^ (ra & 7)) * 8;
    ald[q] = As + (32 * w + 8 * q) * 64;
    int rb = 32 * w + 8 * q + (l >> 3);
    int nt = (n0 >> 6) + (rb >> 6);
    bps[q] = w2t + (((size_t)e * 16 + nt) * 64 + kh * 32) * 4096 + (rb & 63) * 64 + ((l & 7) ^ (rb & 7)) * 8;
    bld[q] = Bs + (32 * w + 8 * q) * 64;
  }

  const int wm = (w >> 1) * 64, wn = (w & 1) * 64;
  const int l15 = l & 15, lg = l >> 4;

  f32x4 acc[4][4];
  const f32x4 zf = {0.f, 0.f, 0.f, 0.f};
#pragma unroll
  for (int mi = 0; mi < 4; ++mi)
#pragma unroll
    for (int ni = 0; ni < 4; ++ni) acc[mi][ni] = zf;

  for (int kt = 0; kt < 32; ++kt) {
#pragma unroll
    for (int q = 0; q < 4; ++q) GLL16(aps[q] + kt * 64, ald[q]);
#pragma unroll
    for (int q = 0; q < 4; ++q) GLL16(bps[q] + kt * 4096, bld[q]);
    __syncthreads();
#pragma unroll
    for (int ks = 0; ks < 2; ++ks) {
      const int kb = ks * 64 + lg * 16;
      bf16x8 af[4];
#pragma unroll
      for (int mi = 0; mi < 4; ++mi)
        af[mi] = *(const bf16x8*)lds_swz(As, wm + mi * 16 + l15, kb);
#pragma unroll
      for (int ni = 0; ni < 4; ++ni) {
        bf16x8 bfb = *(const bf16x8*)lds_swz(Bs, wn + ni * 16 + l15, kb);
#pragma unroll
        for (int mi = 0; mi < 4; ++mi)
          acc[mi][ni] = __builtin_amdgcn_mfma_f32_16x16x32_bf16(af[mi], bfb, acc[mi][ni], 0, 0, 0);
      }
    }
    __syncthreads();
  }

#pragma unroll
  for (int mi = 0; mi < 4; ++mi) {
    const int rb = wm + mi * 16 + lg * 4;
#pragma unroll
    for (int ni = 0; ni < 4; ++ni) {
      const int col = n0 + wn + ni * 16 + l15;
      f32x4 c = acc[mi][ni];
#pragma unroll
      for (int j = 0; j < 4; ++j) {
        int rr = rb + j;
        int id = rowid[rr];
        if (id >= 0)
          unsafeAtomicAdd(&out[(size_t)(id >> 1) * 1024 + col], c[j] * rw[rr]);
      }
    }
  }
}

extern "C" void kernel_launch(void* const* d_in, const int* in_sizes, int n_in,
                              void* d_out, int out_size, void* d_ws, size_t ws_size,
                              hipStream_t stream)
{
  (void)in_sizes; (void)n_in; (void)out_size; (void)ws_size;
  const float* x  = (const float*)d_in[0];
  const float* gw = (const float*)d_in[1];
  const float* w1 = (const float*)d_in[2];
  const float* w3 = (const float*)d_in[3];
  const float* w2 = (const float*)d_in[4];
  float* out   = (float*)d_out;
  float* probs = out + (size_t)4096 * 1024;

  const size_t MB = (size_t)1 << 20;
  char* ws = (char*)d_ws;
  u16*   xb    = (u16*)(ws);
  u16*   H     = (u16*)(ws + 8 * MB);
  u16*   w1t   = (u16*)(ws + 72 * MB);
  u16*   w3t   = (u16*)(ws + 136 * MB);
  u16*   w2t   = (u16*)(ws + 200 * MB);
  float* wa    = (float*)(ws + 264 * MB);
  int*   alist = (int*)(ws + 264 * MB + 32768);
  int*   cnt   = (int*)(ws + 264 * MB + 32768 + 131072);

  hipMemsetAsync(cnt, 0, 8 * sizeof(int), stream);
  hipMemsetAsync(out, 0, (size_t)4096 * 1024 * sizeof(float), stream);
  prep13_k<<<8192, 256, 0, stream>>>(w1, w3, w1t, w3t, x, gw, probs, xb, wa, alist, cnt);
  gemm1w2_k<<<dim3(80, 32, 8), 256, 0, stream>>>(xb, w1t, w3t, alist, cnt, H, w2, w2t);
  gemm2_k<<<dim3(8, 64, 8), 256, 0, stream>>>(H, w2t, alist, cnt, wa, out);
}